// Round 9
// baseline (295.234 us; speedup 1.0000x reference)
//
#include <hip/hip_runtime.h>
#include <hip/hip_fp16.h>

#define N_NODES 100000
#define N_EDGES 1600000
#define N_GRAPHS 128
#define NBUCK 391            // ceil(100000/256) buckets of 256 nodes
#define NBLK 512             // blocks for count/scatter passes
#define NE4 (N_EDGES / 4)    // 400000 int4 elements
#define CHUNK_E4 782         // int4 elements per block (512*782 >= 400000)
#define LDX 136              // LDS stride (halves) for MFMA staging

typedef unsigned long long u64;
typedef unsigned int u32;
typedef unsigned char u8;
typedef _Float16 f16;
typedef f16 half8 __attribute__((ext_vector_type(8)));
typedef f16 half4v __attribute__((ext_vector_type(4)));
typedef float floatx4 __attribute__((ext_vector_type(4)));

// ---------------- pass 1: per-(bucket,block) counts of dst and src ----------------
__global__ __launch_bounds__(256) void k_cnt(const int4* __restrict__ src4,
                                             const int4* __restrict__ dst4,
                                             int* __restrict__ counts_d,
                                             int* __restrict__ counts_s) {
  __shared__ int hd[NBUCK], hs[NBUCK];
  const int t = threadIdx.x, blk = blockIdx.x;
  for (int j = t; j < NBUCK; j += 256) { hd[j] = 0; hs[j] = 0; }
  __syncthreads();
  const int start = blk * CHUNK_E4;
  const int end = min(start + CHUNK_E4, NE4);
  for (int i = start + t; i < end; i += 256) {
    int4 d = dst4[i]; int4 s = src4[i];
    atomicAdd(&hd[d.x >> 8], 1); atomicAdd(&hd[d.y >> 8], 1);
    atomicAdd(&hd[d.z >> 8], 1); atomicAdd(&hd[d.w >> 8], 1);
    atomicAdd(&hs[s.x >> 8], 1); atomicAdd(&hs[s.y >> 8], 1);
    atomicAdd(&hs[s.z >> 8], 1); atomicAdd(&hs[s.w >> 8], 1);
  }
  __syncthreads();
  for (int j = t; j < NBUCK; j += 256) {
    counts_d[j * NBLK + blk] = hd[j];
    counts_s[j * NBLK + blk] = hs[j];
  }
}

// ---------------- pass 2a: per-bucket exclusive scan over blocks (512 wide) ----------
__global__ __launch_bounds__(512) void k_scanA(int* __restrict__ counts_d,
                                               int* __restrict__ counts_s,
                                               int* __restrict__ totals_d,
                                               int* __restrict__ totals_s) {
  __shared__ int s[512];
  const int b = blockIdx.x, t = threadIdx.x;
  int v = counts_d[b * NBLK + t];
  s[t] = v;
  __syncthreads();
  for (int off = 1; off < 512; off <<= 1) {
    int a = (t >= off) ? s[t - off] : 0;
    __syncthreads(); s[t] += a; __syncthreads();
  }
  counts_d[b * NBLK + t] = s[t] - v;
  if (t == 511) totals_d[b] = s[t];
  __syncthreads();
  v = counts_s[b * NBLK + t];
  s[t] = v;
  __syncthreads();
  for (int off = 1; off < 512; off <<= 1) {
    int a = (t >= off) ? s[t - off] : 0;
    __syncthreads(); s[t] += a; __syncthreads();
  }
  counts_s[b * NBLK + t] = s[t] - v;
  if (t == 511) totals_s[b] = s[t];
}

// ---------------- pass 2b: exclusive scan over buckets ----------------
__global__ __launch_bounds__(512) void k_scanB(const int* __restrict__ totals_d,
                                               const int* __restrict__ totals_s,
                                               int* __restrict__ boff_d,
                                               int* __restrict__ boff_s,
                                               int* __restrict__ row_ptr) {
  __shared__ int s[512];
  const int t = threadIdx.x;
  int v = (t < NBUCK) ? totals_d[t] : 0;
  s[t] = v;
  __syncthreads();
  for (int off = 1; off < 512; off <<= 1) {
    int a = (t >= off) ? s[t - off] : 0;
    __syncthreads(); s[t] += a; __syncthreads();
  }
  if (t < NBUCK) boff_d[t] = s[t] - v;
  if (t == 0) { boff_d[NBUCK] = N_EDGES; row_ptr[N_NODES] = N_EDGES; }
  __syncthreads();
  v = (t < NBUCK) ? totals_s[t] : 0;
  s[t] = v;
  __syncthreads();
  for (int off = 1; off < 512; off <<= 1) {
    int a = (t >= off) ? s[t - off] : 0;
    __syncthreads(); s[t] += a; __syncthreads();
  }
  if (t < NBUCK) boff_s[t] = s[t] - v;
  if (t == 0) boff_s[NBUCK] = N_EDGES;
}

// ---------------- pass 3: bucket-scatter packed (dl,src) u32 and src low-bytes ------
__global__ __launch_bounds__(256) void k_scatter(const int4* __restrict__ src4,
                                                 const int4* __restrict__ dst4,
                                                 const int* __restrict__ counts_d,
                                                 const int* __restrict__ counts_s,
                                                 const int* __restrict__ boff_d,
                                                 const int* __restrict__ boff_s,
                                                 u32* __restrict__ ed,
                                                 u8* __restrict__ ssk8) {
  __shared__ int cur_d[NBUCK], cur_s[NBUCK];
  const int t = threadIdx.x, blk = blockIdx.x;
  for (int j = t; j < NBUCK; j += 256) {
    cur_d[j] = boff_d[j] + counts_d[j * NBLK + blk];
    cur_s[j] = boff_s[j] + counts_s[j * NBLK + blk];
  }
  __syncthreads();
  const int start = blk * CHUNK_E4;
  const int end = min(start + CHUNK_E4, NE4);
  for (int i = start + t; i < end; i += 256) {
    int4 d4 = dst4[i]; int4 s4 = src4[i];
    {
      int d = d4.x, s = s4.x;
      int pd = atomicAdd(&cur_d[d >> 8], 1);
      ed[pd] = ((u32)(d & 255) << 24) | (u32)s;
      int ps = atomicAdd(&cur_s[s >> 8], 1);
      ssk8[ps] = (u8)(s & 255);
    }
    {
      int d = d4.y, s = s4.y;
      int pd = atomicAdd(&cur_d[d >> 8], 1);
      ed[pd] = ((u32)(d & 255) << 24) | (u32)s;
      int ps = atomicAdd(&cur_s[s >> 8], 1);
      ssk8[ps] = (u8)(s & 255);
    }
    {
      int d = d4.z, s = s4.z;
      int pd = atomicAdd(&cur_d[d >> 8], 1);
      ed[pd] = ((u32)(d & 255) << 24) | (u32)s;
      int ps = atomicAdd(&cur_s[s >> 8], 1);
      ssk8[ps] = (u8)(s & 255);
    }
    {
      int d = d4.w, s = s4.w;
      int pd = atomicAdd(&cur_d[d >> 8], 1);
      ed[pd] = ((u32)(d & 255) << 24) | (u32)s;
      int ps = atomicAdd(&cur_s[s >> 8], 1);
      ssk8[ps] = (u8)(s & 255);
    }
  }
}

// ------ pass 4: per-bucket CSR finalize + out-degree (fused) ----
__global__ __launch_bounds__(256) void k_bucket_csr(const u32* __restrict__ ed,
                                                    const int* __restrict__ boff_d,
                                                    const u8* __restrict__ ssk8,
                                                    const int* __restrict__ boff_s,
                                                    int* __restrict__ row_ptr,
                                                    float* __restrict__ norm_in,
                                                    float* __restrict__ norm_out,
                                                    int* __restrict__ edge_src) {
  __shared__ int hist[256], scanbuf[256], cursor[256], hist2[256];
  const int b = blockIdx.x, t = threadIdx.x;
  const int base = b << 8;
  hist[t] = 0; hist2[t] = 0;
  __syncthreads();
  const int slo = boff_s[b], shi = boff_s[b + 1];
  for (int i = slo + t; i < shi; i += 256)
    atomicAdd(&hist2[ssk8[i]], 1);
  const int lo = boff_d[b], hi = boff_d[b + 1];
  for (int i = lo + t; i < hi; i += 256)
    atomicAdd(&hist[ed[i] >> 24], 1);
  __syncthreads();
  int node = base + t;
  if (node < N_NODES)
    norm_out[node] = rsqrtf(fmaxf((float)hist2[t], 1.0f));
  int v = hist[t];
  scanbuf[t] = v;
  __syncthreads();
  for (int off = 1; off < 256; off <<= 1) {
    int a = (t >= off) ? scanbuf[t - off] : 0;
    __syncthreads(); scanbuf[t] += a; __syncthreads();
  }
  int excl = scanbuf[t] - v;
  if (node < N_NODES) {
    row_ptr[node] = lo + excl;
    norm_in[node] = rsqrtf(fmaxf((float)v, 1.0f));
  }
  cursor[t] = excl;
  __syncthreads();
  for (int i = lo + t; i < hi; i += 256) {
    u32 e = ed[i];
    int p = atomicAdd(&cursor[e >> 24], 1);
    edge_src[lo + p] = (int)(e & 0x00FFFFFFu);
  }
}

// ---------------- gemm1 (MFMA fp16): h1 = (x * norm_out) @ W1 -> fp16 -------------------
__global__ __launch_bounds__(256) void k_gemm1(const float* __restrict__ x,
                                               const float* __restrict__ W1,
                                               const float* __restrict__ norm_out,
                                               __half* __restrict__ h1h) {
  __shared__ __align__(16) f16 Xs[64 * LDX];
  __shared__ __align__(16) f16 Ws[64 * LDX];
  const int t = threadIdx.x;
  const int row0 = blockIdx.x * 64;

  const float4* W4 = (const float4*)W1;     // 2048 float4 = [k][n4]
  for (int i = t; i < 2048; i += 256) {
    int k = i >> 4, n4 = (i & 15) * 4;
    float4 v = W4[i];
    Ws[(n4 + 0) * LDX + k] = (f16)v.x;
    Ws[(n4 + 1) * LDX + k] = (f16)v.y;
    Ws[(n4 + 2) * LDX + k] = (f16)v.z;
    Ws[(n4 + 3) * LDX + k] = (f16)v.w;
  }
  const float4* x4 = (const float4*)x;
  #pragma unroll
  for (int i = 0; i < 8; ++i) {
    int idx = t + 256 * i;                  // 0..2047
    int r = idx >> 5, c4 = idx & 31;
    int row = row0 + r;
    float4 v = make_float4(0.f, 0.f, 0.f, 0.f);
    if (row < N_NODES) {
      float s = norm_out[row];
      v = x4[(size_t)row * 32 + c4];
      v.x *= s; v.y *= s; v.z *= s; v.w *= s;
    }
    half4v h = { (f16)v.x, (f16)v.y, (f16)v.z, (f16)v.w };
    *(half4v*)&Xs[r * LDX + c4 * 4] = h;
  }
  __syncthreads();

  const int w = t >> 6, l = t & 63;
  const int m = l & 15, quad = l >> 4;
  floatx4 c0 = {0.f,0.f,0.f,0.f}, c1 = {0.f,0.f,0.f,0.f};
  floatx4 c2 = {0.f,0.f,0.f,0.f}, c3 = {0.f,0.f,0.f,0.f};
  const f16* xrow = &Xs[(w * 16 + m) * LDX + quad * 8];
  const f16* wrow = &Ws[m * LDX + quad * 8];
  #pragma unroll
  for (int kb = 0; kb < 4; ++kb) {
    half8 a  = *(const half8*)(xrow + kb * 32);
    half8 b0 = *(const half8*)(wrow + kb * 32);
    half8 b1 = *(const half8*)(wrow + 16 * LDX + kb * 32);
    half8 b2 = *(const half8*)(wrow + 32 * LDX + kb * 32);
    half8 b3 = *(const half8*)(wrow + 48 * LDX + kb * 32);
    c0 = __builtin_amdgcn_mfma_f32_16x16x32_f16(a, b0, c0, 0, 0, 0);
    c1 = __builtin_amdgcn_mfma_f32_16x16x32_f16(a, b1, c1, 0, 0, 0);
    c2 = __builtin_amdgcn_mfma_f32_16x16x32_f16(a, b2, c2, 0, 0, 0);
    c3 = __builtin_amdgcn_mfma_f32_16x16x32_f16(a, b3, c3, 0, 0, 0);
  }
  #pragma unroll
  for (int r = 0; r < 4; ++r) {
    int row = row0 + w * 16 + quad * 4 + r;
    if (row < N_NODES + 1) {                // include zeros dummy row N_NODES
      __half* dst = h1h + (size_t)row * 64 + m;
      dst[0]  = __float2half(c0[r]);
      dst[16] = __float2half(c1[r]);
      dst[32] = __float2half(c2[r]);
      dst[48] = __float2half(c3[r]);
    }
  }
}

// ---------------- fused: gather(h1) -> relu(.*norm_in + b1) -> @W2 * norm_out -> h2 ----
// one wave per node; 8 lanes/edge (uint4 = 8 fp16 feats); 16-edge clamped blocks (2 loads)
__global__ __launch_bounds__(256) void k_gather_l1(const int* __restrict__ row_ptr,
                                                   const int* __restrict__ edge_src,
                                                   const __half* __restrict__ h1h,
                                                   const float* __restrict__ norm_in,
                                                   const float* __restrict__ norm_out,
                                                   const float* __restrict__ b1,
                                                   const float* __restrict__ W2,
                                                   __half* __restrict__ h2h) {
  __shared__ float W2s[64 * 17];   // padded stride 17
  const int t = threadIdx.x;
  for (int i = t; i < 64 * 16; i += 256) W2s[(i >> 4) * 17 + (i & 15)] = W2[i];
  if (blockIdx.x == 0 && t < 16) h2h[(size_t)N_NODES * 16 + t] = __float2half(0.f);
  __syncthreads();

  const int w = t >> 6;
  const int l = t & 63;
  const int n = blockIdx.x * 4 + w;
  const int p = l >> 3;            // edge slot 0..7
  const u32 c = (u32)(l & 7);      // uint4 index within 128B row

  const uint4* __restrict__ h1q = (const uint4*)h1h;
  const int lo = row_ptr[n], hi = row_ptr[n + 1];

  float2 f0 = {0.f,0.f}, f1 = {0.f,0.f}, f2 = {0.f,0.f}, f3 = {0.f,0.f};
  for (int i = lo; i < hi; i += 16) {
    int idx = i + (l & 15);
    int sv = (idx < hi) ? edge_src[idx] : (int)N_NODES;   // clamp to zeros row
    int sa = __shfl(sv, p, 64);
    int sb = __shfl(sv, p + 8, 64);
    uint4 va = h1q[(u32)sa * 8u + c];
    uint4 vb = h1q[(u32)sb * 8u + c];
    float2 g;
    g = __half22float2(*(__half2*)&va.x); f0.x += g.x; f0.y += g.y;
    g = __half22float2(*(__half2*)&va.y); f1.x += g.x; f1.y += g.y;
    g = __half22float2(*(__half2*)&va.z); f2.x += g.x; f2.y += g.y;
    g = __half22float2(*(__half2*)&va.w); f3.x += g.x; f3.y += g.y;
    g = __half22float2(*(__half2*)&vb.x); f0.x += g.x; f0.y += g.y;
    g = __half22float2(*(__half2*)&vb.y); f1.x += g.x; f1.y += g.y;
    g = __half22float2(*(__half2*)&vb.z); f2.x += g.x; f2.y += g.y;
    g = __half22float2(*(__half2*)&vb.w); f3.x += g.x; f3.y += g.y;
  }
  float hr[8] = { f0.x, f0.y, f1.x, f1.y, f2.x, f2.y, f3.x, f3.y };
  #pragma unroll
  for (int e = 0; e < 8; ++e) {
    hr[e] += __shfl_xor(hr[e], 8, 64);
    hr[e] += __shfl_xor(hr[e], 16, 64);
    hr[e] += __shfl_xor(hr[e], 32, 64);
  }
  // lane holds feats 8c..8c+7 (duplicated across p)
  const float ni = norm_in[n];
  const float4 bA = ((const float4*)b1)[c * 2];
  const float4 bB = ((const float4*)b1)[c * 2 + 1];
  hr[0] = fmaxf(hr[0] * ni + bA.x, 0.f);
  hr[1] = fmaxf(hr[1] * ni + bA.y, 0.f);
  hr[2] = fmaxf(hr[2] * ni + bA.z, 0.f);
  hr[3] = fmaxf(hr[3] * ni + bA.w, 0.f);
  hr[4] = fmaxf(hr[4] * ni + bB.x, 0.f);
  hr[5] = fmaxf(hr[5] * ni + bB.y, 0.f);
  hr[6] = fmaxf(hr[6] * ni + bB.z, 0.f);
  hr[7] = fmaxf(hr[7] * ni + bB.w, 0.f);

  // dot: out j = sum_k h1r[k]*W2[k][j]; k split over 4 groups of 16 (p2 = l>>4)
  const int j = l & 15, p2 = l >> 4;
  float partial = 0.f;
  #pragma unroll
  for (int e = 0; e < 8; ++e) {
    float v0 = __shfl(hr[e], p2 * 2, 64);       // k = p2*16 + e
    float v1 = __shfl(hr[e], p2 * 2 + 1, 64);   // k = p2*16 + 8 + e
    partial += v0 * W2s[(p2 * 16 + e) * 17 + j];
    partial += v1 * W2s[(p2 * 16 + 8 + e) * 17 + j];
  }
  partial += __shfl_xor(partial, 16, 64);
  partial += __shfl_xor(partial, 32, 64);
  if (l < 16) h2h[(size_t)n * 16 + l] = __float2half(norm_out[n] * partial);
}

// ---------------- gather layer2: agg2 = norm_in * sum_edges h2[src]  (16 feats) --------
__global__ __launch_bounds__(256) void k_gather_l2(const int* __restrict__ row_ptr,
                                                   const int* __restrict__ edge_src,
                                                   const __half* __restrict__ h2h,
                                                   const float* __restrict__ norm_in,
                                                   float* __restrict__ agg2) {
  const int t = threadIdx.x;
  const int w = t >> 6;
  const int l = t & 63;
  const int n = blockIdx.x * 4 + w;
  const int f2 = l & 7;
  const int p = l >> 3;            // 8 edge slices

  const u32* __restrict__ h2u = (const u32*)h2h;
  const int lo = row_ptr[n], hi = row_ptr[n + 1];

  float ax = 0.f, ay = 0.f, bx = 0.f, by = 0.f;
  for (int base = lo; base < hi; base += 16) {
    int i1 = base + p, i2 = base + p + 8;
    int s0 = (i1 < hi) ? edge_src[i1] : (int)N_NODES;
    int s1 = (i2 < hi) ? edge_src[i2] : (int)N_NODES;
    u32 v0 = h2u[(u32)s0 * 8u + (u32)f2];
    u32 v1 = h2u[(u32)s1 * 8u + (u32)f2];
    float2 g0 = __half22float2(*(__half2*)&v0);
    float2 g1 = __half22float2(*(__half2*)&v1);
    ax += g0.x; ay += g0.y;
    bx += g1.x; by += g1.y;
  }
  float sx = ax + bx, sy = ay + by;
  sx += __shfl_xor(sx, 8, 64);  sy += __shfl_xor(sy, 8, 64);
  sx += __shfl_xor(sx, 16, 64); sy += __shfl_xor(sy, 16, 64);
  sx += __shfl_xor(sx, 32, 64); sy += __shfl_xor(sy, 32, 64);
  if (l < 8) {
    float ni = norm_in[n];
    ((float2*)agg2)[(size_t)n * 8 + f2] = make_float2(sx * ni, sy * ni);
  }
}

// ---------------- per-graph mean pool (gid sorted, no atomics) ----------------
__global__ __launch_bounds__(256) void k_pool(const float* __restrict__ agg2,
                                              const float* __restrict__ b2,
                                              const int* __restrict__ gid,
                                              float* __restrict__ out) {
  const int g = blockIdx.x;
  __shared__ int s_lo, s_hi;
  if (threadIdx.x == 0) {
    int a = 0, b = N_NODES;
    while (a < b) { int m = (a + b) >> 1; if (gid[m] < g) a = m + 1; else b = m; }
    s_lo = a;
    b = N_NODES;
    while (a < b) { int m = (a + b) >> 1; if (gid[m] < g + 1) a = m + 1; else b = m; }
    s_hi = a;
  }
  __syncthreads();
  const int lo = s_lo, hi = s_hi, cnt = hi - lo;
  const int j = threadIdx.x & 15;
  const int r = threadIdx.x >> 4;
  float acc = 0.f;
  for (int n = lo + r; n < hi; n += 16)
    acc += agg2[(size_t)n * 16 + j];

  __shared__ float red[256];
  red[threadIdx.x] = acc;
  __syncthreads();
  #pragma unroll
  for (int s = 8; s > 0; s >>= 1) {
    if (r < s) red[threadIdx.x] += red[threadIdx.x + s * 16];
    __syncthreads();
  }
  if (r == 0)
    out[g * 16 + j] = (cnt > 0) ? (red[j] / (float)cnt + b2[j]) : 0.0f;
}

extern "C" void kernel_launch(void* const* d_in, const int* in_sizes, int n_in,
                              void* d_out, int out_size, void* d_ws, size_t ws_size,
                              hipStream_t stream) {
  const float* x   = (const float*)d_in[0];
  const float* W1  = (const float*)d_in[1];
  const float* b1  = (const float*)d_in[2];
  const float* W2  = (const float*)d_in[3];
  const float* b2  = (const float*)d_in[4];
  const int*   src = (const int*)d_in[5];
  const int*   dst = (const int*)d_in[6];
  const int*   gid = (const int*)d_in[7];
  float* out = (float*)d_out;

  const size_t N = N_NODES, E = N_EDGES;
  float* wsf = (float*)d_ws;
  int*   wsi = (int*)d_ws;

  // persistent: norm_out, norm_in, row_ptr, edge_src
  float* norm_out = wsf;                                  // [N]
  float* norm_in  = wsf + N;                              // [N]
  int*   row_ptr  = wsi + 2 * N;                          // [N+1]
  int*   edge_src = wsi + 3 * N + 16;                     // [E]
  size_t S = 3 * N + 16 + E;                              // scratch base (words)
  // sort scratch (dead after k_bucket_csr; overlapped by h1h/h2h/agg2 afterwards)
  u8*    ssk8     = (u8*)(wsi + S);                       // [E bytes = E/4 words]
  int*   counts_d = wsi + S + 400000;                     // [NBUCK*NBLK = 200192]
  int*   counts_s = wsi + S + 600192;                     // [200192]
  int*   totals_d = wsi + S + 800384;                     // [392]
  int*   totals_s = wsi + S + 800776;                     // [392]
  int*   boff_d   = wsi + S + 801168;                     // [392]
  int*   boff_s   = wsi + S + 801560;                     // [392]
  u32*   ed       = (u32*)(wsi + S + 801952);             // [E]
  // reuse region (after CSR build); h1h/h2h have a zeros dummy row at index N
  __half* h1h     = (__half*)(wsi + S);                   // [64*(N+1) halves]
  __half* h2h     = (__half*)(wsi + S + 32 * N + 32);     // [16*(N+1) halves]
  float*  agg2    = (float*)(wsi + S + 40 * N + 40);      // [16N]

  const int4* src4 = (const int4*)src;
  const int4* dst4 = (const int4*)dst;

  k_cnt       <<<NBLK, 256, 0, stream>>>(src4, dst4, counts_d, counts_s);
  k_scanA     <<<NBUCK, 512, 0, stream>>>(counts_d, counts_s, totals_d, totals_s);
  k_scanB     <<<1, 512, 0, stream>>>(totals_d, totals_s, boff_d, boff_s, row_ptr);
  k_scatter   <<<NBLK, 256, 0, stream>>>(src4, dst4, counts_d, counts_s, boff_d, boff_s, ed, ssk8);
  k_bucket_csr<<<NBUCK, 256, 0, stream>>>(ed, boff_d, ssk8, boff_s, row_ptr, norm_in, norm_out, edge_src);
  k_gemm1     <<<(N_NODES + 64) / 64, 256, 0, stream>>>(x, W1, norm_out, h1h);
  k_gather_l1 <<<N_NODES / 4, 256, 0, stream>>>(row_ptr, edge_src, h1h, norm_in, norm_out, b1, W2, h2h);
  k_gather_l2 <<<N_NODES / 4, 256, 0, stream>>>(row_ptr, edge_src, h2h, norm_in, agg2);
  k_pool      <<<N_GRAPHS, 256, 0, stream>>>(agg2, b2, gid, out);
}